// Round 9
// baseline (85.421 us; speedup 1.0000x reference)
//
#include <hip/hip_runtime.h>

#define HH 136
#define WW 240
#define HW (HH * WW)
#define DS 8
#define OW (DS * WW)   // 1920
#define OH (DS * HH)   // 1088

typedef float vf4 __attribute__((ext_vector_type(4)));

// R8 (76.4 us) + T14 async-STAGE split. R8's chunk loop serialized
// stage->barrier->compute->barrier, so loads for chunk c+1 couldn't issue
// until chunk c's compute drained. Now: issue chunk c+1's 6 vf4 loads into
// REGISTERS (no consumer) -> compute chunk c from LDS (hides HBM latency)
// -> barrier -> ds_write regs -> barrier. Single 23 KB buffer keeps 5-6
// blocks/CU (20-24 waves) of TLP; launch_bounds(256,5) caps VGPR ~102 to
// fit pre[6]+accumulators without spill (R6: spill >> occupancy loss).
__global__ __launch_bounds__(256, 5) void upflow_kernel(
    const float* __restrict__ flow,
    const float* __restrict__ mask,
    float* __restrict__ out) {
  __shared__ float lm[24][WW];  // 23040 B

  int h = blockIdx.x;   // 0..135
  int ni = blockIdx.y;  // n*8 + i
  int i = ni & 7;
  int n = ni >> 3;
  int tid = threadIdx.x;
  int wid = tid >> 6, lane = tid & 63;
  int px = tid;  // compute column for tid < 240
  bool stager = lane < 60;

  // mask row base for this (n, i, h); channel offset (k*64 + j)*HW is uniform.
  const float* mrow = mask + ((size_t)n * 576 + i * 8) * HW + (size_t)h * WW;

  // 3x3 flow neighborhood in registers (tiny, L2-resident), pre-scaled.
  float f0[9], f1[9];
  if (px < WW) {
    const float* fb0 = flow + (size_t)(n * 2 + 0) * HW;
    const float* fb1 = flow + (size_t)(n * 2 + 1) * HW;
#pragma unroll
    for (int dy = 0; dy < 3; ++dy) {
      int hh = h + dy - 1;
      bool rok = (hh >= 0) && (hh < HH);
#pragma unroll
      for (int dx = 0; dx < 3; ++dx) {
        int k = dy * 3 + dx;
        int cc = px + dx - 1;
        bool ok = rok && (cc >= 0) && (cc < WW);
        int idx = hh * WW + cc;
        f0[k] = ok ? 8.0f * fb0[idx] : 0.0f;
        f1[k] = ok ? 8.0f * fb1[idx] : 0.0f;
      }
    }
  }

  const float L2E = 1.4426950408889634f;
  float sj[8], d0j[8], d1j[8];
#pragma unroll
  for (int j = 0; j < 8; ++j) { sj[j] = 0.f; d0j[j] = 0.f; d1j[j] = 0.f; }

  vf4 pre[6];
  // Prologue: stage chunk 0 (wave wid stages rows wid+4t; 960 B per row).
  if (stager) {
#pragma unroll
    for (int it = 0; it < 6; ++it) {
      int rr = wid + it * 4;         // 0..23
      int kk = rr >> 3, j = rr & 7;  // k-triplet row, j
      pre[it] = *(const vf4*)(mrow + (size_t)(kk * 64 + j) * HW + lane * 4);
    }
#pragma unroll
    for (int it = 0; it < 6; ++it) {
      int rr = wid + it * 4;
      *(vf4*)&lm[rr][lane * 4] = pre[it];
    }
  }
  __syncthreads();

#pragma unroll
  for (int chunk = 0; chunk < 3; ++chunk) {
    // Issue next chunk's loads NOW — consumed only after the next barrier.
    if (chunk < 2 && stager) {
#pragma unroll
      for (int it = 0; it < 6; ++it) {
        int rr = wid + it * 4;
        int kk = rr >> 3, j = rr & 7;
        pre[it] = *(const vf4*)(
            mrow + (size_t)(((chunk + 1) * 3 + kk) * 64 + j) * HW + lane * 4);
      }
    }
    // Compute chunk from LDS (stride-1 reads: 2 lanes/bank = free).
    if (px < WW) {
#pragma unroll
      for (int j = 0; j < 8; ++j) {
#pragma unroll
        for (int kk = 0; kk < 3; ++kk) {
          const int k = chunk * 3 + kk;  // static after unroll
          float e = exp2f(lm[kk * 8 + j][px] * L2E);  // no max-subtraction
          sj[j] += e;
          d0j[j] += e * f0[k];
          d1j[j] += e * f1[k];
        }
      }
    }
    if (chunk < 2) {
      __syncthreads();  // all reads of lm done
      if (stager) {
#pragma unroll
        for (int it = 0; it < 6; ++it) {
          int rr = wid + it * 4;
          *(vf4*)&lm[rr][lane * 4] = pre[it];  // vmcnt waits land here
        }
      }
      __syncthreads();  // lm refilled
    }
  }

  if (px < WW) {
    // out[n][c][h*8+i][px*8+j]: 32 B contiguous per lane per channel;
    // block writes one fully dense 1920-float row per channel (R4 shape).
    size_t ob0 =
        ((size_t)(n * 2 + 0) * OH + (size_t)(h * 8 + i)) * (size_t)OW + px * 8;
    size_t ob1 = ob0 + (size_t)OH * OW;
    float r0 = 1.0f / sj[0], r1 = 1.0f / sj[1], r2 = 1.0f / sj[2],
          r3 = 1.0f / sj[3], r4 = 1.0f / sj[4], r5 = 1.0f / sj[5],
          r6 = 1.0f / sj[6], r7 = 1.0f / sj[7];
    vf4 a = {d0j[0] * r0, d0j[1] * r1, d0j[2] * r2, d0j[3] * r3};
    vf4 b = {d0j[4] * r4, d0j[5] * r5, d0j[6] * r6, d0j[7] * r7};
    vf4 c = {d1j[0] * r0, d1j[1] * r1, d1j[2] * r2, d1j[3] * r3};
    vf4 d = {d1j[4] * r4, d1j[5] * r5, d1j[6] * r6, d1j[7] * r7};
    *(vf4*)(out + ob0) = a;
    *(vf4*)(out + ob0 + 4) = b;
    *(vf4*)(out + ob1) = c;
    *(vf4*)(out + ob1 + 4) = d;
  }
}

extern "C" void kernel_launch(void* const* d_in, const int* in_sizes, int n_in,
                              void* d_out, int out_size, void* d_ws, size_t ws_size,
                              hipStream_t stream) {
  const float* flow = (const float*)d_in[0];
  const float* mask = (const float*)d_in[1];
  float* out = (float*)d_out;
  dim3 grid(HH, 32);  // x = h, y = n*8 + i
  upflow_kernel<<<grid, 256, 0, stream>>>(flow, mask, out);
}

// Round 10
// 76.716 us; speedup vs baseline: 1.1135x; 1.1135x over previous
//
#include <hip/hip_runtime.h>

#define HH 136
#define WW 240
#define HW (HH * WW)
#define DS 8
#define OW (DS * WW)   // 1920
#define OH (DS * HH)   // 1088
#define CROWS 18       // rows per chunk
#define NCH 4          // 4 chunks x 18 = 72 (k,j) rows

typedef float vf4 __attribute__((ext_vector_type(4)));

// R8 producer/consumer, tuned for BLOCK CONCURRENCY (R9 lesson: inter-block
// stagger is what hides the stage phase; intra-block prefetch at -1 block/CU
// LOST 12%. So: more blocks, cheaper stages).
//  - 4 chunks of 18 rows: LDS 17280 B -> LDS allows 9 blocks/CU (was 6).
//  - global_load_lds staging: HBM->LDS direct, no VGPR round trip, 5
//    fire-and-forget instructions per lane; __syncthreads' vmcnt(0) drain is
//    the completion wait. LDS dest = wave-uniform row base + lane*16 (the
//    required pattern); global src is per-lane.
//  - launch_bounds(256,7): cap ~73 VGPR >= ~55 live, 7 blocks = 28 waves/CU.
//  - Compute/store: unchanged from R8 (no-max softmax verified R6-R9; R4
//    store shape: thread owns 32 B/channel, back-to-back vf4s).
__device__ __forceinline__ void gload_lds16(const float* g, float* l) {
  __builtin_amdgcn_global_load_lds(
      (const __attribute__((address_space(1))) void*)g,
      (__attribute__((address_space(3))) void*)l, 16, 0, 0);
}

__global__ __launch_bounds__(256, 7) void upflow_kernel(
    const float* __restrict__ flow,
    const float* __restrict__ mask,
    float* __restrict__ out) {
  __shared__ float lm[CROWS][WW];  // 17280 B

  int h = blockIdx.x;   // 0..135
  int ni = blockIdx.y;  // n*8 + i
  int i = ni & 7;
  int n = ni >> 3;
  int tid = threadIdx.x;
  int wid = tid >> 6, lane = tid & 63;
  int px = tid;  // compute column for tid < 240
  bool stager = lane < 60;

  // mask row base for this (n, i, h); per-row offset ((g>>3)*64 + (g&7))*HW
  // is wave-uniform.
  const float* mrow = mask + ((size_t)n * 576 + i * 8) * HW + (size_t)h * WW;

  // 3x3 flow neighborhood in registers (tiny, L2-resident), pre-scaled.
  float f0[9], f1[9];
  if (px < WW) {
    const float* fb0 = flow + (size_t)(n * 2 + 0) * HW;
    const float* fb1 = flow + (size_t)(n * 2 + 1) * HW;
#pragma unroll
    for (int dy = 0; dy < 3; ++dy) {
      int hh = h + dy - 1;
      bool rok = (hh >= 0) && (hh < HH);
#pragma unroll
      for (int dx = 0; dx < 3; ++dx) {
        int k = dy * 3 + dx;
        int cc = px + dx - 1;
        bool ok = rok && (cc >= 0) && (cc < WW);
        int idx = hh * WW + cc;
        f0[k] = ok ? 8.0f * fb0[idx] : 0.0f;
        f1[k] = ok ? 8.0f * fb1[idx] : 0.0f;
      }
    }
  }

  const float L2E = 1.4426950408889634f;
  float sj[8], d0j[8], d1j[8];
#pragma unroll
  for (int j = 0; j < 8; ++j) { sj[j] = 0.f; d0j[j] = 0.f; d1j[j] = 0.f; }

#pragma unroll
  for (int c = 0; c < NCH; ++c) {
    // Stage chunk c: wave wid stages rows wid+4t (waves 0,1: 5 rows; 2,3: 4).
    if (stager) {
#pragma unroll
      for (int t = 0; t < 5; ++t) {
        int rr = wid + 4 * t;
        if (rr < CROWS) {
          int g = c * CROWS + rr;  // global row 0..71: k = g>>3, j = g&7
          const float* src =
              mrow + (size_t)((g >> 3) * 64 + (g & 7)) * HW + lane * 4;
          gload_lds16(src, &lm[rr][0]);  // HW adds lane*16 to the LDS base
        }
      }
    }
    __syncthreads();  // vmcnt(0) drain completes the LDS fill
    if (px < WW) {
#pragma unroll
      for (int rr = 0; rr < CROWS; ++rr) {
        const int g = c * CROWS + rr;          // static after unroll
        const int k = g >> 3, j = g & 7;       // static
        float e = exp2f(lm[rr][px] * L2E);     // no max-subtraction
        sj[j] += e;
        d0j[j] += e * f0[k];
        d1j[j] += e * f1[k];
      }
    }
    if (c < NCH - 1) __syncthreads();  // lm reads done before refill
  }

  if (px < WW) {
    // out[n][c][h*8+i][px*8+j]: 32 B contiguous per lane per channel; block
    // writes one fully dense 1920-float row per channel.
    size_t ob0 =
        ((size_t)(n * 2 + 0) * OH + (size_t)(h * 8 + i)) * (size_t)OW + px * 8;
    size_t ob1 = ob0 + (size_t)OH * OW;
    float r0 = 1.0f / sj[0], r1 = 1.0f / sj[1], r2 = 1.0f / sj[2],
          r3 = 1.0f / sj[3], r4 = 1.0f / sj[4], r5 = 1.0f / sj[5],
          r6 = 1.0f / sj[6], r7 = 1.0f / sj[7];
    vf4 a = {d0j[0] * r0, d0j[1] * r1, d0j[2] * r2, d0j[3] * r3};
    vf4 b = {d0j[4] * r4, d0j[5] * r5, d0j[6] * r6, d0j[7] * r7};
    vf4 c = {d1j[0] * r0, d1j[1] * r1, d1j[2] * r2, d1j[3] * r3};
    vf4 d = {d1j[4] * r4, d1j[5] * r5, d1j[6] * r6, d1j[7] * r7};
    *(vf4*)(out + ob0) = a;
    *(vf4*)(out + ob0 + 4) = b;
    *(vf4*)(out + ob1) = c;
    *(vf4*)(out + ob1 + 4) = d;
  }
}

extern "C" void kernel_launch(void* const* d_in, const int* in_sizes, int n_in,
                              void* d_out, int out_size, void* d_ws, size_t ws_size,
                              hipStream_t stream) {
  const float* flow = (const float*)d_in[0];
  const float* mask = (const float*)d_in[1];
  float* out = (float*)d_out;
  dim3 grid(HH, 32);  // x = h, y = n*8 + i
  upflow_kernel<<<grid, 256, 0, stream>>>(flow, mask, out);
}

// Round 11
// 74.663 us; speedup vs baseline: 1.1441x; 1.0275x over previous
//
#include <hip/hip_runtime.h>

#define HH 136
#define WW 240
#define HW (HH * WW)
#define DS 8
#define OW (DS * WW)   // 1920
#define OH (DS * HH)   // 1088
#define CROWS 12       // rows per chunk (3 per wave -> uniform vmcnt count)
#define NCH 6          // 6 chunks x 12 = 72 (k,j) rows

typedef float vf4 __attribute__((ext_vector_type(4)));

// R10 + T3/T4-lite pipeline (R9/R10 post-mortems: block concurrency is
// saturated; the residual wall is the per-chunk vmcnt(0) drain at
// __syncthreads serializing HBM latency with compute in EVERY block).
//  - Double-buffered LDS lm[2][12][240] = 23 KB -> 7 blocks/CU (no
//    concurrency loss), staged via global_load_lds (no VGPR cost).
//  - Counted vmcnt: issue chunk c+1 (3 gload_lds per wave, uniform), then
//    s_waitcnt vmcnt(3) = "batch c landed, batch c+1 still in flight",
//    then raw s_barrier. Latency of c+1 hides under compute of c.
//  - asm memory clobbers around raw barriers pin compiler-generated
//    ds_reads inside their phase (no __syncthreads = no auto-fences).
//  - Compute/store unchanged (no-max softmax verified R6-R10; R4 store
//    shape: thread owns 32 B/channel, dense row per block).
__device__ __forceinline__ void gload_lds16(const float* g, float* l) {
  __builtin_amdgcn_global_load_lds(
      (const __attribute__((address_space(1))) void*)g,
      (__attribute__((address_space(3))) void*)l, 16, 0, 0);
}

__global__ __launch_bounds__(256, 7) void upflow_kernel(
    const float* __restrict__ flow,
    const float* __restrict__ mask,
    float* __restrict__ out) {
  __shared__ float lm[2][CROWS][WW];  // 2 x 11520 B

  int h = blockIdx.x;   // 0..135
  int ni = blockIdx.y;  // n*8 + i
  int i = ni & 7;
  int n = ni >> 3;
  int tid = threadIdx.x;
  int wid = tid >> 6, lane = tid & 63;
  int px = tid;  // compute column for tid < 240
  bool stager = lane < 60;

  const float* mrow = mask + ((size_t)n * 576 + i * 8) * HW + (size_t)h * WW;

  // Prologue: stage chunk 0 into buf0 first (latency overlaps flow loads).
  if (stager) {
#pragma unroll
    for (int t = 0; t < 3; ++t) {
      int rr = wid + 4 * t;  // 3 rows per wave, uniform
      gload_lds16(mrow + (size_t)((rr >> 3) * 64 + (rr & 7)) * HW + lane * 4,
                  &lm[0][rr][0]);
    }
  }

  // 3x3 flow neighborhood in registers (tiny, L2-resident), pre-scaled.
  float f0[9], f1[9];
  if (px < WW) {
    const float* fb0 = flow + (size_t)(n * 2 + 0) * HW;
    const float* fb1 = flow + (size_t)(n * 2 + 1) * HW;
#pragma unroll
    for (int dy = 0; dy < 3; ++dy) {
      int hh = h + dy - 1;
      bool rok = (hh >= 0) && (hh < HH);
#pragma unroll
      for (int dx = 0; dx < 3; ++dx) {
        int k = dy * 3 + dx;
        int cc = px + dx - 1;
        bool ok = rok && (cc >= 0) && (cc < WW);
        int idx = hh * WW + cc;
        f0[k] = ok ? 8.0f * fb0[idx] : 0.0f;
        f1[k] = ok ? 8.0f * fb1[idx] : 0.0f;
      }
    }
  }

  const float L2E = 1.4426950408889634f;
  float sj[8], d0j[8], d1j[8];
#pragma unroll
  for (int j = 0; j < 8; ++j) { sj[j] = 0.f; d0j[j] = 0.f; d1j[j] = 0.f; }

#pragma unroll
  for (int c = 0; c < NCH; ++c) {
    if (c + 1 < NCH) {
      // Issue next chunk's batch (consumed only after the NEXT iteration's
      // wait) into the other buffer.
      if (stager) {
#pragma unroll
        for (int t = 0; t < 3; ++t) {
          int rr = wid + 4 * t;
          int g = (c + 1) * CROWS + rr;  // global row: k = g>>3, j = g&7
          gload_lds16(
              mrow + (size_t)((g >> 3) * 64 + (g & 7)) * HW + lane * 4,
              &lm[(c + 1) & 1][rr][0]);
        }
      }
      // Wait for batch c only (3 newest = batch c+1 stay in flight).
      asm volatile("s_waitcnt vmcnt(3)" ::: "memory");
    } else {
      asm volatile("s_waitcnt vmcnt(0)" ::: "memory");
    }
    __builtin_amdgcn_s_barrier();   // all waves' batch-c data visible
    asm volatile("" ::: "memory");  // ds_reads may not hoist above

    if (px < WW) {
#pragma unroll
      for (int rr = 0; rr < CROWS; ++rr) {
        const int g = c * CROWS + rr;     // static after unroll
        const int k = g >> 3, j = g & 7;  // static
        float e = exp2f(lm[c & 1][rr][px] * L2E);  // no max-subtraction
        sj[j] += e;
        d0j[j] += e * f0[k];
        d1j[j] += e * f1[k];
      }
    }

    if (c + 1 < NCH) {
      asm volatile("" ::: "memory");  // ds_reads may not sink below
      __builtin_amdgcn_s_barrier();   // buf[c&1] reads done; refill legal
      asm volatile("" ::: "memory");
    }
  }

  if (px < WW) {
    // out[n][c][h*8+i][px*8+j]: 32 B contiguous per lane per channel; block
    // writes one fully dense 1920-float row per channel.
    size_t ob0 =
        ((size_t)(n * 2 + 0) * OH + (size_t)(h * 8 + i)) * (size_t)OW + px * 8;
    size_t ob1 = ob0 + (size_t)OH * OW;
    float r0 = 1.0f / sj[0], r1 = 1.0f / sj[1], r2 = 1.0f / sj[2],
          r3 = 1.0f / sj[3], r4 = 1.0f / sj[4], r5 = 1.0f / sj[5],
          r6 = 1.0f / sj[6], r7 = 1.0f / sj[7];
    vf4 a = {d0j[0] * r0, d0j[1] * r1, d0j[2] * r2, d0j[3] * r3};
    vf4 b = {d0j[4] * r4, d0j[5] * r5, d0j[6] * r6, d0j[7] * r7};
    vf4 c = {d1j[0] * r0, d1j[1] * r1, d1j[2] * r2, d1j[3] * r3};
    vf4 d = {d1j[4] * r4, d1j[5] * r5, d1j[6] * r6, d1j[7] * r7};
    *(vf4*)(out + ob0) = a;
    *(vf4*)(out + ob0 + 4) = b;
    *(vf4*)(out + ob1) = c;
    *(vf4*)(out + ob1 + 4) = d;
  }
}

extern "C" void kernel_launch(void* const* d_in, const int* in_sizes, int n_in,
                              void* d_out, int out_size, void* d_ws, size_t ws_size,
                              hipStream_t stream) {
  const float* flow = (const float*)d_in[0];
  const float* mask = (const float*)d_in[1];
  float* out = (float*)d_out;
  dim3 grid(HH, 32);  // x = h, y = n*8 + i
  upflow_kernel<<<grid, 256, 0, stream>>>(flow, mask, out);
}